// Round 14
// baseline (155.166 us; speedup 1.0000x reference)
//
#include <hip/hip_runtime.h>

#define NN 16
constexpr int BB = 32, CIN = 64, HH = 112, WW = 112;
constexpr int HWC = HH * WW;          // 12544
constexpr int COUT = 128, HW2 = 56 * 56;
constexpr int NE = 64;
constexpr int NQ = HWC / 4;           // 3136 quads per image
constexpr int QW = 784;               // quads per window (4 windows/image)
constexpr int NCG = 16;               // channel groups of 4
constexpr int PPI = 64;               // partials per image (4 windows * 16 cg)
constexpr int PF4 = COUT * HW2 / 4;   // 100352 float4 per batch
constexpr int SBPB = 28;              // scale blocks per batch (28*3584 = PF4)
constexpr int JPT = 14;               // float4 iters per scale thread
constexpr int PREF = 6;               // register prefetch depth

// ---- Kernel 1: contiguous-run 1x1 conv + direct segment scatter ----
// Block = (image b, window qi of 784 quads, channel-group cg of 4).
// Thread owns quads {3t, 3t+1, 3t+2} (+ tail quad 768+t for t<16) of the
// window and loops the 4 channels IN-REGISTER: wave's in-flight loads cover
// a contiguous 3KB run per plane (vs 1KB/50KB-stride before). No ps[] LDS.
// cg==0 additionally contributes row/col/cnt. All loops static (no spill).
__global__ __launch_bounds__(256) void k_conv_seg(
    const float* __restrict__ Bfor, const int* __restrict__ seg,
    const float* __restrict__ convw, float* __restrict__ part)
{
    __shared__ float acc8[8 * 80];      // [replica][node*5+st], bank-skewed
    const int tid = threadIdx.x;
    const int bid = blockIdx.x;
    const int b   = bid >> 6;           // image
    const int qi  = (bid >> 4) & 3;    // window
    const int cg  = bid & 15;           // channel group (4 channels)

    for (int i = tid; i < 8 * 80; i += 256) acc8[i] = 0.f;
    __syncthreads();

    const int q0 = qi * QW;             // window base quad
    float4 a[4];
    #pragma unroll
    for (int k = 0; k < 4; ++k) a[k] = make_float4(0.f, 0.f, 0.f, 0.f);

    const float* base = Bfor + (size_t)(b * CIN + cg * 4) * HWC + (size_t)q0 * 4;
    #pragma unroll
    for (int c = 0; c < 4; ++c) {
        const float wc = convw[cg * 4 + c];
        const float* pl = base + (size_t)c * HWC;
        float4 v0 = *reinterpret_cast<const float4*>(pl + (3 * tid + 0) * 4);
        float4 v1 = *reinterpret_cast<const float4*>(pl + (3 * tid + 1) * 4);
        float4 v2 = *reinterpret_cast<const float4*>(pl + (3 * tid + 2) * 4);
        a[0].x = fmaf(v0.x, wc, a[0].x); a[0].y = fmaf(v0.y, wc, a[0].y);
        a[0].z = fmaf(v0.z, wc, a[0].z); a[0].w = fmaf(v0.w, wc, a[0].w);
        a[1].x = fmaf(v1.x, wc, a[1].x); a[1].y = fmaf(v1.y, wc, a[1].y);
        a[1].z = fmaf(v1.z, wc, a[1].z); a[1].w = fmaf(v1.w, wc, a[1].w);
        a[2].x = fmaf(v2.x, wc, a[2].x); a[2].y = fmaf(v2.y, wc, a[2].y);
        a[2].z = fmaf(v2.z, wc, a[2].z); a[2].w = fmaf(v2.w, wc, a[2].w);
        if (tid < 16) {                  // tail quads 768..783 (static guard)
            float4 v3 = *reinterpret_cast<const float4*>(pl + (768 + tid) * 4);
            a[3].x = fmaf(v3.x, wc, a[3].x); a[3].y = fmaf(v3.y, wc, a[3].y);
            a[3].z = fmaf(v3.z, wc, a[3].z); a[3].w = fmaf(v3.w, wc, a[3].w);
        }
    }

    // ---- scatter (replica-skewed LDS atomics; cg0 owns row/col/cnt) ----
    const int* segb = seg + (size_t)b * HWC;
    const int rep = tid & 7;
    float* ar = &acc8[rep * 80];
    #pragma unroll
    for (int k = 0; k < 4; ++k) {
        if (k < 3 || tid < 16) {
            const int q = (k < 3) ? (q0 + 3 * tid + k) : (q0 + 768 + tid);
            const int p = q * 4;
            const int4 sg = *reinterpret_cast<const int4*>(segb + p);
            atomicAdd(ar + sg.x * 5 + 2, a[k].x);
            atomicAdd(ar + sg.y * 5 + 2, a[k].y);
            atomicAdd(ar + sg.z * 5 + 2, a[k].z);
            atomicAdd(ar + sg.w * 5 + 2, a[k].w);
            if (cg == 0) {
                const float row  = (float)(p / WW);   // WW%4==0
                const float col0 = (float)(p % WW);
                atomicAdd(ar + sg.x * 5 + 0, row);
                atomicAdd(ar + sg.y * 5 + 0, row);
                atomicAdd(ar + sg.z * 5 + 0, row);
                atomicAdd(ar + sg.w * 5 + 0, row);
                atomicAdd(ar + sg.x * 5 + 1, col0);
                atomicAdd(ar + sg.y * 5 + 1, col0 + 1.f);
                atomicAdd(ar + sg.z * 5 + 1, col0 + 2.f);
                atomicAdd(ar + sg.w * 5 + 1, col0 + 3.f);
                atomicAdd(ar + sg.x * 5 + 3, 1.f);
                atomicAdd(ar + sg.y * 5 + 3, 1.f);
                atomicAdd(ar + sg.z * 5 + 3, 1.f);
                atomicAdd(ar + sg.w * 5 + 3, 1.f);
            }
        }
    }
    __syncthreads();

    if (tid < 64) {
        const int node = tid >> 2, st = tid & 3;
        float v = 0.f;
        #pragma unroll
        for (int r = 0; r < 8; ++r) v += acc8[r * 80 + node * 5 + st];
        part[(size_t)bid * 64 + tid] = v;   // bid == (b*4+qi)*16+cg
    }
}

// ------- Kernel 2: fused graph stage + scale (R9 verbatim; 64 partials) ----
__global__ __launch_bounds__(256) void k_graph_scale(
    const float* __restrict__ part, const int* __restrict__ src,
    const int* __restrict__ dst,  const float* __restrict__ convb,
    const float* __restrict__ W1, const float* __restrict__ b1,
    const float* __restrict__ W2, const float* __restrict__ b2,
    const float* __restrict__ fcw, const float* __restrict__ fcb,
    const float* __restrict__ Bfon, float* __restrict__ out)
{
    const int b    = blockIdx.x / SBPB;
    const int blkb = blockIdx.x % SBPB;
    const int tid  = threadIdx.x;
    const int w0   = blkb * (JPT * 256);   // contiguous window in [0, PF4)

    __shared__ float X[NN][4];
    __shared__ float A[NN][NN];
    __shared__ float nrm[NN];
    __shared__ float h1s[NN][32];
    __shared__ float agg[NN][32];
    __shared__ float pred[4][64];
    __shared__ float gpart[2][COUT];
    __shared__ float Gs[COUT];

    const float4* bf4 = reinterpret_cast<const float4*>(Bfon) + (size_t)b * PF4;
    float4*       ob4 = reinterpret_cast<float4*>(out)        + (size_t)b * PF4;

    // ---- issue Bfon prefetch (depth PREF) before Phase A ----
    float4 r[JPT];
    #pragma unroll
    for (int j = 0; j < PREF; ++j) r[j] = bf4[w0 + j * 256 + tid];

    // ---- Phase A: tiny graph network (redundant across SBPB blocks) ----
    {   // reduce 64 partials: 4 chunks x 16, coalesced
        const int id = tid & 63, chunk = tid >> 6;
        float v = 0.f;
        #pragma unroll
        for (int j = 0; j < 16; ++j)
            v += part[(size_t)(b * PPI + chunk * 16 + j) * 64 + id];
        pred[chunk][id] = v;
    }
    for (int i = tid; i < NN * NN; i += 256) ((float*)A)[i] = 0.f;
    __syncthreads();

    if (tid < 64) {
        const int node = tid >> 2, st = tid & 3;
        X[node][st] = pred[0][tid] + pred[1][tid] + pred[2][tid] + pred[3][tid];
    }
    __syncthreads();

    if (tid < NN) {        // raw sums -> features (conv bias folded in)
        const float cnt = X[tid][3];
        const float cs  = fmaxf(cnt, 1.f);
        X[tid][0] = X[tid][0] / cs;
        X[tid][1] = X[tid][1] / cs;
        X[tid][2] = (X[tid][2] + cnt * convb[0]) / cs;
    }
    __syncthreads();

    // normalize feature cols 2,3 across nodes (mean, std ddof=1)
    if (tid < 2) {
        const int c = 2 + tid;
        float mu = 0.f;
        for (int i = 0; i < NN; ++i) mu += X[i][c];
        mu *= (1.f / NN);
        float var = 0.f;
        for (int i = 0; i < NN; ++i) { const float d = X[i][c] - mu; var = fmaf(d, d, var); }
        var *= (1.f / (NN - 1));
        const float inv = 1.f / (sqrtf(var) + 1.f);
        for (int i = 0; i < NN; ++i) X[i][c] = (X[i][c] - mu) * inv;
    }
    // build adjacency (idempotent set-to-1)
    if (tid >= 64 && tid < 64 + NE) {
        const int e = tid - 64;
        const int s = src[b * NE + e], d = dst[b * NE + e];
        A[s][d] = 1.f;
        A[d][s] = 1.f;
    }
    __syncthreads();

    if (tid < NN) {
        float rs = 0.f;
        for (int j = 0; j < NN; ++j) rs += A[tid][j];
        nrm[tid] = 1.f / sqrtf(fmaxf(rs, 1.f));
    }
    __syncthreads();

    if (tid < NN * 4) {    // agg1 (16x4)
        const int i = tid >> 2, k = tid & 3;
        float s = 0.f;
        for (int j = 0; j < NN; ++j) s = fmaf(A[i][j] * nrm[j], X[j][k], s);
        agg[i][k] = s;
    }
    __syncthreads();

    for (int t = tid; t < NN * 32; t += 256) {   // h1 (16x32)
        const int i = t >> 5, f = t & 31;
        float s = 0.f;
        #pragma unroll
        for (int k = 0; k < 4; ++k) s = fmaf(agg[i][k], W1[k * 32 + f], s);
        h1s[i][f] = fmaxf(fmaf(nrm[i], s, b1[f]), 0.f);
    }
    __syncthreads();

    for (int t = tid; t < NN * 32; t += 256) {   // agg2 (16x32)
        const int i = t >> 5, k = t & 31;
        float s = 0.f;
        for (int j = 0; j < NN; ++j) s = fmaf(A[i][j] * nrm[j], h1s[j][k], s);
        agg[i][k] = s;
    }
    __syncthreads();

    {   // h2 + FC, i-range split across 2 half-blocks
        const int f = tid & 127, half = tid >> 7;
        float g = 0.f;
        const float bf = b2[f];
        for (int i = half * 8; i < half * 8 + 8; ++i) {
            float s = 0.f;
            #pragma unroll
            for (int k = 0; k < 32; ++k) s = fmaf(agg[i][k], W2[k * COUT + f], s);
            g = fmaf(fcw[i], fmaxf(fmaf(nrm[i], s, bf), 0.f), g);
        }
        gpart[half][f] = g;
    }
    __syncthreads();
    if (tid < COUT) Gs[tid] = gpart[0][tid] + gpart[1][tid] + fcb[0];
    __syncthreads();

    // ---- Phase B: rolling register pipeline over the contiguous window ----
    #pragma unroll
    for (int j = 0; j < JPT; ++j) {
        if (j + PREF < JPT) r[j + PREF] = bf4[w0 + (j + PREF) * 256 + tid];
        const int t = w0 + j * 256 + tid;
        const float g = Gs[t / (HW2 / 4)];   // 784 float4 per (b,c) plane
        ob4[t] = make_float4(r[j].x * g, r[j].y * g, r[j].z * g, r[j].w * g);
    }
}

extern "C" void kernel_launch(void* const* d_in, const int* in_sizes, int n_in,
                              void* d_out, int out_size, void* d_ws, size_t ws_size,
                              hipStream_t stream)
{
    const float* Bfor  = (const float*)d_in[0];
    const float* Bfon  = (const float*)d_in[1];
    const int*   seg   = (const int*)d_in[2];
    const int*   src   = (const int*)d_in[3];
    const int*   dst   = (const int*)d_in[4];
    const float* convw = (const float*)d_in[5];
    const float* convb = (const float*)d_in[6];
    const float* W1    = (const float*)d_in[7];
    const float* b1    = (const float*)d_in[8];
    const float* W2    = (const float*)d_in[9];
    const float* b2    = (const float*)d_in[10];
    const float* fcw   = (const float*)d_in[11];
    const float* fcb   = (const float*)d_in[12];

    float* part = (float*)d_ws;           // 2048 * 64 floats = 512 KB
    float* out  = (float*)d_out;

    k_conv_seg<<<BB * PPI, 256, 0, stream>>>(Bfor, seg, convw, part);
    k_graph_scale<<<BB * SBPB, 256, 0, stream>>>(part, src, dst, convb,
                                                 W1, b1, W2, b2, fcw, fcb,
                                                 Bfon, out);
}